// Round 5
// baseline (619.525 us; speedup 1.0000x reference)
//
#include <hip/hip_runtime.h>
#include <cstdint>

// Problem constants (LocalizedFiltering: B=4, S=4096, D=2048, DH=1024)
#define BB 4
#define SS 4096           // power of 2: t = r & 4095, b = r >> 12
#define DD 2048
#define DH 1024
#define MM (BB * SS)      // 16384 rows
#define EPSV 1e-6f

typedef unsigned short u16;
typedef __bf16 bf16x8 __attribute__((ext_vector_type(8)));
typedef float f32x4 __attribute__((ext_vector_type(4)));

// ---------- helpers ----------

__device__ __forceinline__ u16 f2bf(float f) {           // RNE f32 -> bf16 bits
    uint32_t u = __float_as_uint(f);
    u += 0x7fffu + ((u >> 16) & 1u);
    return (u16)(u >> 16);
}

// async global->LDS, 16B per lane. LDS dest is wave-uniform base + lane*16.
__device__ __forceinline__ void async16(const void* g, void* l) {
    __builtin_amdgcn_global_load_lds(
        (const __attribute__((address_space(1))) uint32_t*)g,
        (__attribute__((address_space(3))) uint32_t*)l,
        16, 0, 0);
}

#define FENCE asm volatile("" ::: "memory")

// ---------- fused converts / packs (round-5: 9 -> 5 launches) ----------

// cvt x -> bf16, AND emit lf1 cache rows (t == S-1) as f32 on the fly.
__global__ void cvt_x_lf1(const float* __restrict__ in, u16* __restrict__ out,
                          float* __restrict__ lf1out) {
    long i = (long)blockIdx.x * blockDim.x + threadIdx.x;   // 4-elem group index
    float4 v = *(const float4*)(in + i * 4);
    ushort4 o;
    o.x = f2bf(v.x); o.y = f2bf(v.y); o.z = f2bf(v.z); o.w = f2bf(v.w);
    *(ushort4*)(out + i * 4) = o;
    int r = (int)(i >> 9);                 // row = (i*4) / 2048
    if ((r & (SS - 1)) == (SS - 1)) {      // last timestep of a batch
        int col = (int)((i * 4) & (DD - 1));
        *(float4*)(lf1out + (r >> 12) * DD + col) = v;
    }
}

// One kernel for: pack w1 (blocks [0,8192)), pack w2 ([8192,16384)),
// cvt lf1 cache ([16384,16392)), cvt lf2 cache ([16392,16396)).
__global__ void prep_small(const float* __restrict__ w1, u16* __restrict__ W1b,
                           const float* __restrict__ w2, u16* __restrict__ W2b,
                           const float* __restrict__ lf1c, u16* __restrict__ c1,
                           const float* __restrict__ lf2c, u16* __restrict__ c2) {
    int bid = blockIdx.x;
    int tid = threadIdx.x;
    if (bid < 8192) {                       // w1: [DH, D, 2] -> [DH, 2*D], Dd=2048
        int idx = bid * 256 + tid;
        int e = idx >> 11, d = idx & 2047;
        float2 v = *(const float2*)(w1 + (long)idx * 2);
        long rb = (long)e * (DD * 2);
        W1b[rb + d] = f2bf(v.x);
        W1b[rb + DD + d] = f2bf(v.y);
    } else if (bid < 16384) {               // w2: [D, DH, 2] -> [D, 2*DH], Dd=1024
        int idx = (bid - 8192) * 256 + tid;
        int e = idx >> 10, d = idx & 1023;
        float2 v = *(const float2*)(w2 + (long)idx * 2);
        long rb = (long)e * (DH * 2);
        W2b[rb + d] = f2bf(v.x);
        W2b[rb + DH + d] = f2bf(v.y);
    } else if (bid < 16392) {               // lf1 cache cvt: B*D = 8192 elems, 4/thread
        int i = (bid - 16384) * 256 + tid;  // 0..2047
        float4 v = *(const float4*)(lf1c + (long)i * 4);
        ushort4 o;
        o.x = f2bf(v.x); o.y = f2bf(v.y); o.z = f2bf(v.z); o.w = f2bf(v.w);
        *(ushort4*)(c1 + (long)i * 4) = o;
    } else {                                // lf2 cache cvt: B*DH = 4096 elems
        int i = (bid - 16392) * 256 + tid;  // 0..1023
        float4 v = *(const float4*)(lf2c + (long)i * 4);
        ushort4 o;
        o.x = f2bf(v.x); o.y = f2bf(v.y); o.z = f2bf(v.z); o.w = f2bf(v.w);
        *(ushort4*)(c2 + (long)i * 4) = o;
    }
}

// ---------- shifted 2-tap GEMM: 256x256 tile, 8-wave, ring-4 K-half pipeline ----------
//
// Schedule = round-3 (best verified: 169/167 us per gemm), minus s_setprio
// (m190: setprio slightly NEGATIVE on lockstep barrier-synced GEMMs; ours is).
// Four schedule structures (4-phase / 2-phase / ring-4 / ring-4+reg-dbuf) all
// measured 167-178 us -> the window cost is schedule-invariant; keep the
// simplest verified one.
//
// LDS (128 KiB): ring of 4 K-half slots per matrix, slot = step & 3.
//   A slot u at elems [u*8192, +8192): 256 rows x 32 k-elems (row r at r*32+k).
//   B slot u at 32768 + u*8192, same shape (rows = output cols).
// Swizzle (verified conflict-free rounds 1-4): 16B-slot s of row r holds
//   global chunk s ^ ((r>>1)&3); staged via pre-swizzled GLOBAL address
//   (global_load_lds dest is linear base+lane*16), read with the same XOR.
// Step s: { 12 ds_read_b128 (B first); stage(s+3) -> slot (s+3)&3;
//           32 MFMA (compiler fine-grained lgkm); vmcnt(8); barrier }
// WAR: slot (s+3)&3 == (s-1)&3 last read in step s-1; those reads retired
//   before each wave passed barrier B_{s-1}. RAW: vmcnt(8) at B_s drains
//   stage(s+1); 2+ windows of flight >> 900-cyc HBM latency.
// Prologue stages 0,1,2 (12 loads), vmcnt(8), barrier. Tail peels 8/4/0/none.
//
// C[r,n] = sum_{k<KD} Bt[n,k]*Aprev[r,k] + sum_{k<KD} Bt[n,KD+k]*Acur[r,k]
// Aprev row r = (r%S==0) ? cache[r/S] : A[r-1]
// Step u sources Aprev when u < NT, else Acur at u*32-KD.
// MODE 1: out bf16 [M,NN] + bias; rows with t==S-1 also stored f32 to lf2out
// MODE 2: out f32  [M,NN] + bias + residual xres
template <int KD, int MODE>
__launch_bounds__(512, 2)
__global__ void gemm2tap(const u16* __restrict__ A,       // [M, KD] bf16
                         const u16* __restrict__ cache,   // [B, KD] bf16
                         const u16* __restrict__ Bt,      // [NN, 2*KD] bf16
                         const float* __restrict__ bias,  // [NN]
                         u16* __restrict__ obf,           // MODE 1
                         float* __restrict__ lf2out,      // MODE 1
                         const float* __restrict__ xres,  // MODE 2
                         float* __restrict__ yout)        // MODE 2
{
    constexpr int KTOT = 2 * KD;
    constexpr int NT = KTOT / 64;      // K-tiles of 64
    constexpr int NS = 2 * NT;         // K-half steps of 32
    constexpr int NN = (MODE == 1) ? DH : DD;
    static_assert(NS % 4 == 0 && NS >= 8, "ring-4 schedule needs NS % 4 == 0, NS >= 8");

    const int tid = threadIdx.x;
    const int lane = tid & 63;
    const int wave = tid >> 6;         // 8 waves: wm = wave>>2 (2), wn = wave&3 (4)
    const int bm = blockIdx.x;
    const int bn = blockIdx.y;

    __shared__ __align__(16) u16 sm[65536];   // 128 KiB

    // ---- staging addressing ----
    const int srow = wave * 16 + (lane >> 2);          // row within 128-row half
    const int skc  = (lane & 3) ^ ((lane >> 3) & 3);   // pre-swizzled global chunk
    const int sRowA = wave * 512;                      // wave-uniform LDS elem offset

    const u16 *aPrev0, *aPrev1, *aCur0, *aCur1, *bPtr0, *bPtr1;
    {
        long r0 = (long)bm * 256 + srow;
        long r1 = r0 + 128;
        aCur0 = A + r0 * KD + skc * 8;
        aCur1 = A + r1 * KD + skc * 8;
        aPrev0 = ((((int)r0) & (SS - 1)) == 0) ? (cache + (r0 >> 12) * KD + skc * 8)
                                               : (A + (r0 - 1) * KD + skc * 8);
        aPrev1 = ((((int)r1) & (SS - 1)) == 0) ? (cache + (r1 >> 12) * KD + skc * 8)
                                               : (A + (r1 - 1) * KD + skc * 8);
        long n0l = (long)bn * 256 + srow;
        bPtr0 = Bt + n0l * KTOT + skc * 8;
        bPtr1 = Bt + (n0l + 128) * KTOT + skc * 8;
    }

    // stage K-half step U_ into ring slot SLOT_ (A: rows 0..127 then 128..255; B same)
#define STAGE(SLOT_, U_) do {                                                  \
        const int _u = (U_);                                                   \
        const u16 *_g0, *_g1;                                                  \
        if (_u < NT) { _g0 = aPrev0 + _u * 32; _g1 = aPrev1 + _u * 32; }       \
        else { _g0 = aCur0 + (_u - NT) * 32; _g1 = aCur1 + (_u - NT) * 32; }   \
        async16(_g0, sm + (SLOT_) * 8192 + sRowA);                             \
        async16(_g1, sm + (SLOT_) * 8192 + 4096 + sRowA);                      \
        async16(bPtr0 + _u * 32, sm + 32768 + (SLOT_) * 8192 + sRowA);         \
        async16(bPtr1 + _u * 32, sm + 32768 + (SLOT_) * 8192 + 4096 + sRowA);  \
    } while (0)

    // ---- fragment read addressing ----
    const int frow = lane & 15;
    const int fquad = lane >> 4;
    const int wm128 = (wave >> 2) * 128;
    const int wn64  = (wave & 3) * 64;
    const int fq8s = (fquad ^ ((frow >> 1) & 3)) * 8;  // swizzled 16B chunk (elems)
    const int afb = (wm128 + frow) * 32 + fq8s;
    const int bfb = (wn64 + frow) * 32 + fq8s;

    f32x4 acc[8][4];
#pragma unroll
    for (int i = 0; i < 8; ++i)
#pragma unroll
        for (int j = 0; j < 4; ++j)
            acc[i][j] = (f32x4){0.f, 0.f, 0.f, 0.f};

#define MFMA_(D_, A_, B_) D_ = __builtin_amdgcn_mfma_f32_16x16x32_bf16(A_, B_, D_, 0, 0, 0)

    // One K-half step: reads (B first), stage for U3_, MFMA, vmcnt, one barrier.
#define STEP(SLOT_, U3_, DOSTG_, VMS_)                                         \
  {                                                                            \
    const u16* aro = sm + (SLOT_) * 8192;                                      \
    const u16* bro = sm + 32768 + (SLOT_) * 8192;                              \
    bf16x8 bq[4], af[8];                                                       \
    _Pragma("unroll")                                                          \
    for (int nf = 0; nf < 4; ++nf)                                             \
        bq[nf] = *(const bf16x8*)(bro + bfb + nf * 512);                       \
    _Pragma("unroll")                                                          \
    for (int mf = 0; mf < 8; ++mf)                                             \
        af[mf] = *(const bf16x8*)(aro + afb + mf * 512);                       \
    if (DOSTG_) STAGE((((SLOT_) + 3) & 3), (U3_));                             \
    _Pragma("unroll")                                                          \
    for (int mf = 0; mf < 8; ++mf)                                             \
        _Pragma("unroll")                                                      \
        for (int nf = 0; nf < 4; ++nf)                                         \
            MFMA_(acc[mf][nf], af[mf], bq[nf]);                                \
    asm volatile(VMS_ ::: "memory");                                           \
    FENCE; __builtin_amdgcn_s_barrier(); FENCE;                                \
  }

    // ---- prologue: stage steps 0,1,2 (12 loads) in issue order ----
    STAGE(0, 0); FENCE;
    STAGE(1, 1); FENCE;
    STAGE(2, 2);
    asm volatile("s_waitcnt vmcnt(8)" ::: "memory");   // step 0 landed
    FENCE; __builtin_amdgcn_s_barrier(); FENCE;

    // ---- main loop: steps 0 .. NS-5 (full staging, uniform vmcnt(8)) ----
    for (int s = 0; s < NS - 4; s += 4) {
        STEP(0, s + 3, 1, "s_waitcnt vmcnt(8)");
        STEP(1, s + 4, 1, "s_waitcnt vmcnt(8)");
        STEP(2, s + 5, 1, "s_waitcnt vmcnt(8)");
        STEP(3, s + 6, 1, "s_waitcnt vmcnt(8)");
    }
    // ---- tail: steps NS-4 .. NS-1 ----
    STEP(0, NS - 1, 1, "s_waitcnt vmcnt(8)");   // stages the last K-half
    STEP(1, 0, 0, "s_waitcnt vmcnt(4)");
    STEP(2, 0, 0, "s_waitcnt vmcnt(0)");
    STEP(3, 0, 0, "");                          // last step: no wait needed

#undef STEP
#undef STAGE

    // ---- epilogue; C/D layout: col = lane&15, row = (lane>>4)*4 + v ----
    const long m0 = (long)bm * 256 + wm128;
    const int n0 = bn * 256 + wn64;
#pragma unroll
    for (int mf = 0; mf < 8; ++mf) {
#pragma unroll
        for (int nf = 0; nf < 4; ++nf) {
            const int n = n0 + nf * 16 + frow;
            const float bv = bias[n];
#pragma unroll
            for (int v = 0; v < 4; ++v) {
                const long m = m0 + mf * 16 + fquad * 4 + v;
                float val = acc[mf][nf][v] + bv;
                if (MODE == 1) {
                    obf[m * NN + n] = f2bf(val);
                    if ((((int)m) & (SS - 1)) == (SS - 1))
                        lf2out[(m >> 12) * NN + n] = val;   // new lf2 cache (f32)
                } else {
                    val += xres[m * NN + n];                // residual in f32
                    yout[m * NN + n] = val;
                }
            }
        }
    }
}

// ---------- RMSNorm (in-place on d_out rows) ----------

__global__ void rmsnorm_inplace(float* __restrict__ y, const float* __restrict__ lnw) {
    const long r = blockIdx.x;
    float* row = y + r * DD;
    const int tid = threadIdx.x;

    float4 v0 = *(float4*)(row + tid * 4);
    float4 v1 = *(float4*)(row + 1024 + tid * 4);
    float s = v0.x * v0.x + v0.y * v0.y + v0.z * v0.z + v0.w * v0.w
            + v1.x * v1.x + v1.y * v1.y + v1.z * v1.z + v1.w * v1.w;
#pragma unroll
    for (int off = 32; off; off >>= 1) s += __shfl_xor(s, off, 64);

    __shared__ float red[4];
    if ((tid & 63) == 0) red[tid >> 6] = s;
    __syncthreads();
    float tot = red[0] + red[1] + red[2] + red[3];
    float inv = rsqrtf(tot * (1.0f / DD) + EPSV);

    float4 w0 = *(const float4*)(lnw + tid * 4);
    float4 w1 = *(const float4*)(lnw + 1024 + tid * 4);
    v0.x *= inv * w0.x; v0.y *= inv * w0.y; v0.z *= inv * w0.z; v0.w *= inv * w0.w;
    v1.x *= inv * w1.x; v1.y *= inv * w1.y; v1.z *= inv * w1.z; v1.w *= inv * w1.w;
    *(float4*)(row + tid * 4) = v0;
    *(float4*)(row + 1024 + tid * 4) = v1;
}

// ---------- launch ----------

extern "C" void kernel_launch(void* const* d_in, const int* in_sizes, int n_in,
                              void* d_out, int out_size, void* d_ws, size_t ws_size,
                              hipStream_t stream) {
    const float* x    = (const float*)d_in[0];   // [M, D]
    const float* lf1c = (const float*)d_in[1];   // [B, D]
    const float* lf2c = (const float*)d_in[2];   // [B, DH]
    const float* w1   = (const float*)d_in[3];   // [DH, D, 2]
    const float* b1   = (const float*)d_in[4];   // [DH]
    const float* w2   = (const float*)d_in[5];   // [D, DH, 2]
    const float* b2   = (const float*)d_in[6];   // [D]
    const float* lnw  = (const float*)d_in[7];   // [D]

    float* out    = (float*)d_out;                        // lf_output [M, D]
    float* lf1out = out + (long)MM * DD;                  // [B, D]
    float* lf2out = lf1out + (long)BB * DD;               // [B, DH]

    char* ws = (char*)d_ws;
    u16* Xbf  = (u16*)ws; ws += (long)MM * DD * 2;        // 67.1 MB
    u16* o1bf = (u16*)ws; ws += (long)MM * DH * 2;        // 33.6 MB
    u16* W1b  = (u16*)ws; ws += (long)DH * (2 * DD) * 2;  // 8.4 MB
    u16* W2b  = (u16*)ws; ws += (long)DD * (2 * DH) * 2;  // 8.4 MB
    u16* c1   = (u16*)ws; ws += (long)BB * DD * 2;
    u16* c2   = (u16*)ws; ws += (long)BB * DH * 2;

    // 1) converts & weight packing (fused: 2 launches instead of 6)
    cvt_x_lf1<<<32768, 256, 0, stream>>>(x, Xbf, lf1out);
    prep_small<<<16396, 256, 0, stream>>>(w1, W1b, w2, W2b, lf1c, c1, lf2c, c2);

    // 2) conv1 GEMM: [M, 2D] x [2D, DH] -> o1 bf16 (+ lf2 rows f32)
    gemm2tap<DD, 1><<<dim3(MM / 256, DH / 256), 512, 0, stream>>>(
        Xbf, c1, W1b, b1, o1bf, lf2out, nullptr, nullptr);

    // 3) conv2 GEMM: [M, 2DH] x [2DH, D] -> y = o2 + x (f32, into d_out)
    gemm2tap<DH, 2><<<dim3(MM / 256, DD / 256), 512, 0, stream>>>(
        o1bf, c2, W2b, b2, nullptr, nullptr, x, out);

    // 4) RMSNorm in place
    rmsnorm_inplace<<<MM, 256, 0, stream>>>(out, lnw);
}